// Round 4
// baseline (2980.145 us; speedup 1.0000x reference)
//
#include <hip/hip_runtime.h>
#include <cstdint>
#include <cstddef>

// ---------------------------------------------------------------------------
// DeepCNNLSTM_EncoderMOE on MI355X (gfx950)
// Round 4: gate-fused LSTM (thread d owns i,f,g,o of h-dim d; 1 wave/SIMD via
// amdgpu_waves_per_eu(1,1) -> 512 VGPR budget; one barrier/step, no gbuf).
// GN stats+apply fused into one LDS-tile kernel.
// ---------------------------------------------------------------------------

#define DEVI __device__ __forceinline__

typedef _Float16 f16;
typedef _Float16 f16x8 __attribute__((ext_vector_type(8)));
typedef _Float16 f16x2 __attribute__((ext_vector_type(2)));
typedef _Float16 f16x4v __attribute__((ext_vector_type(4)));
typedef float    f32x4 __attribute__((ext_vector_type(4)));
typedef unsigned int u32;
typedef unsigned short u16;

static constexpr int B   = 64;
static constexpr int T   = 512;
static constexpr int NC  = 10;

// ---- workspace layout (bytes) ----
constexpr size_t SZ_WS1 = (size_t)5*64*32*2;
constexpr size_t SZ_WS2 = (size_t)5*128*64*2;
constexpr size_t SZ_WS3 = (size_t)5*256*128*2;
constexpr size_t SZ_WE1 = 8*SZ_WS1;
constexpr size_t SZ_WE2 = 8*SZ_WS2;
constexpr size_t SZ_WE3 = 8*SZ_WS3;
constexpr size_t SZ_WR  = (size_t)5*128*32*2;
constexpr size_t SZ_WIH = (size_t)1024*256*2;
constexpr size_t SZ_WHH = (size_t)128*1024*4;
constexpr size_t SZ_ACT0 = (size_t)B*T*32*2;
constexpr size_t SZ_A1   = (size_t)B*T*64*2;
constexpr size_t SZ_A2   = (size_t)B*T*128*2;
constexpr size_t SZ_RACT = (size_t)B*T*128*2;
constexpr size_t SZ_CONV = (size_t)B*T*256*2;
constexpr size_t SZ_HMIX = (size_t)B*T*256*4;
constexpr size_t SZ_AMIX = (size_t)B*T*256*2;
constexpr size_t SZ_U    = (size_t)B*T*1024*2;
constexpr size_t SZ_STAT = (size_t)B*8*2*4;
constexpr size_t SZ_RH   = (size_t)B*128*4;
constexpr size_t SZ_WSEL = (size_t)B*8*4;
constexpr size_t SZ_HT   = (size_t)B*256*4;

constexpr size_t OFF_WS1  = 0;
constexpr size_t OFF_WS2  = OFF_WS1 + SZ_WS1;
constexpr size_t OFF_WS3  = OFF_WS2 + SZ_WS2;
constexpr size_t OFF_WE1  = OFF_WS3 + SZ_WS3;
constexpr size_t OFF_WE2  = OFF_WE1 + SZ_WE1;
constexpr size_t OFF_WE3  = OFF_WE2 + SZ_WE2;
constexpr size_t OFF_WR   = OFF_WE3 + SZ_WE3;
constexpr size_t OFF_WIH  = OFF_WR  + SZ_WR;
constexpr size_t OFF_WHH  = OFF_WIH + SZ_WIH;
constexpr size_t OFF_ACT0 = OFF_WHH + SZ_WHH;
constexpr size_t OFF_A1   = OFF_ACT0 + SZ_ACT0;
constexpr size_t OFF_A2   = OFF_A1 + SZ_A1;
constexpr size_t OFF_RACT = OFF_A2 + SZ_A2;
constexpr size_t OFF_CONV = OFF_RACT + SZ_RACT;
constexpr size_t OFF_HMIX = OFF_CONV + SZ_CONV;
constexpr size_t OFF_AMIX = OFF_HMIX + SZ_HMIX;
constexpr size_t OFF_U    = OFF_AMIX + SZ_AMIX;
constexpr size_t OFF_STAT = OFF_U + SZ_U;
constexpr size_t OFF_RH   = OFF_STAT + SZ_STAT;
constexpr size_t OFF_WSEL = OFF_RH + SZ_RH;
constexpr size_t OFF_HT   = OFF_WSEL + SZ_WSEL;
constexpr size_t WS_TOTAL = OFF_HT + SZ_HT;

DEVI float geluf(float x){ return 0.5f*x*(1.f + erff(x*0.70710678118654752f)); }
DEVI float fsig(float x){ return 1.f/(1.f + __expf(-x)); }
DEVI float ftanh(float x){ float e = __expf(-2.f*x); return (1.f-e)/(1.f+e); }

// ---------------------------------------------------------------------------
// Weight prep
// ---------------------------------------------------------------------------
DEVI void fill_convw(f16* dst, const float* src, int COUT, int CI, int CIP, int idx){
  int s  = idx / (COUT*CIP);
  int r  = idx - s*(COUT*CIP);
  int co = r / CIP;
  int ci = r - co*CIP;
  float v = (ci < CI) ? src[((size_t)co*CI + ci)*5 + s] : 0.f;
  dst[idx] = (f16)v;
}

__global__ __launch_bounds__(256) void k_prep_w(
    const float* eW1, const float* eW2, const float* eW3,
    const float* sW1, const float* sW2, const float* sW3, const float* rW,
    const float* Wih, const float* Whh, char* ws)
{
  int i = blockIdx.x*256 + threadIdx.x;
  if (i < 10240){ fill_convw((f16*)(ws+OFF_WS1), sW1, 64, 16, 32, i); return; } i -= 10240;
  if (i < 40960){ fill_convw((f16*)(ws+OFF_WS2), sW2, 128, 64, 64, i); return; } i -= 40960;
  if (i < 163840){ fill_convw((f16*)(ws+OFF_WS3), sW3, 256, 128, 128, i); return; } i -= 163840;
  if (i < 81920){ int e=i/10240, r=i-e*10240;
    fill_convw((f16*)(ws+OFF_WE1)+ (size_t)e*10240, eW1 + (size_t)e*64*16*5, 64, 16, 32, r); return; } i -= 81920;
  if (i < 327680){ int e=i/40960, r=i-e*40960;
    fill_convw((f16*)(ws+OFF_WE2)+ (size_t)e*40960, eW2 + (size_t)e*128*64*5, 128, 64, 64, r); return; } i -= 327680;
  if (i < 1310720){ int e=i/163840, r=i-e*163840;
    fill_convw((f16*)(ws+OFF_WE3)+ (size_t)e*163840, eW3 + (size_t)e*163840, 256, 128, 128, r); return; } i -= 1310720;
  if (i < 20480){ fill_convw((f16*)(ws+OFF_WR), rW, 128, 16, 32, i); return; } i -= 20480;
  if (i < 262144){ // W_ih (256,1024) -> [j][k]
    int j = i >> 8, k = i & 255;
    ((f16*)(ws+OFF_WIH))[i] = (f16)Wih[(size_t)k*1024 + j]; return; } i -= 262144;
  if (i < 131072){ // W_hh (256,1024) -> packed row-pairs [pair][1024]
    int i2 = i >> 10, j = i & 1023;
    f16 a = (f16)Whh[(size_t)(2*i2)*1024 + j];
    f16 b = (f16)Whh[(size_t)(2*i2+1)*1024 + j];
    u32 u = (u32)__builtin_bit_cast(unsigned short, a)
          | ((u32)__builtin_bit_cast(unsigned short, b) << 16);
    ((u32*)(ws+OFF_WHH))[i] = u; return; }
}

__global__ __launch_bounds__(256) void k_prep_x(const float* __restrict__ x, char* ws){
  int idx = blockIdx.x*256 + threadIdx.x;
  if (idx >= B*T*32) return;
  int b = idx/(T*32); int r = idx - b*(T*32); int t = r >> 5; int c = r & 31;
  f16 v = (c < 16) ? (f16)x[((size_t)b*16 + c)*T + t] : (f16)0.f;
  ((f16*)(ws+OFF_ACT0))[idx] = v;
}

// ---------------------------------------------------------------------------
// Conv / GEMM via MFMA f16
// ---------------------------------------------------------------------------
template<int CIN, int NSHIFT>
__global__ __launch_bounds__(256) void k_conv(
    const f16* __restrict__ act, const f16* __restrict__ wt,
    f16* __restrict__ outp, const float* __restrict__ bias,
    const float* __restrict__ bsel, int esel, int COUT)
{
  int mt = blockIdx.x;
  int b  = mt >> 3;
  int t0 = (mt & 7) << 6;
  if (bsel && bsel[b*8 + esel] == 0.f) return;
  int n0   = blockIdx.y << 6;
  int tid  = threadIdx.x;
  int wave = tid >> 6, lane = tid & 63;
  int lr = lane & 15, lk = lane >> 4;

  f32x4 acc[4];
  #pragma unroll
  for (int nf=0; nf<4; ++nf) acc[nf] = f32x4{0.f,0.f,0.f,0.f};

  const f16* abase = act + (size_t)b*T*CIN;
  int trow = t0 + wave*16 + lr;

  #pragma unroll
  for (int s=0; s<NSHIFT; ++s){
    int tg = (NSHIFT==5) ? (trow + s - 2) : trow;
    bool valid = (unsigned)tg < (unsigned)T;
    const f16* arow = abase + (long)tg*CIN + lk*8;
    #pragma unroll
    for (int c0=0; c0<CIN; c0+=32){
      f16x8 af = {(f16)0,(f16)0,(f16)0,(f16)0,(f16)0,(f16)0,(f16)0,(f16)0};
      if (valid) af = *(const f16x8*)(arow + c0);
      #pragma unroll
      for (int nf=0; nf<4; ++nf){
        int col = n0 + nf*16 + lr;
        f16x8 bf = *(const f16x8*)(wt + ((size_t)s*COUT + col)*CIN + c0 + lk*8);
        acc[nf] = __builtin_amdgcn_mfma_f32_16x16x32_f16(af, bf, acc[nf], 0, 0, 0);
      }
    }
  }

  #pragma unroll
  for (int nf=0; nf<4; ++nf){
    int col = n0 + nf*16 + lr;
    float bv = bias ? bias[col] : 0.f;
    #pragma unroll
    for (int r=0; r<4; ++r){
      int trw = t0 + wave*16 + lk*4 + r;
      size_t o = ((size_t)b*T + trw)*COUT + col;
      outp[o] = (f16)(acc[nf][r] + bv);
    }
  }
}

// ---------------------------------------------------------------------------
// Fused GroupNorm (stats + normalize + GELU) per (b,g) via LDS tile.
// MODE 0: write f16 act. MODE 1: hmix = v (f32). MODE 2: hmix += w*v.
// ---------------------------------------------------------------------------
template<int CPG, int MODE>
__global__ __launch_bounds__(256) void k_gn(
    const f16* __restrict__ xin,
    const float* __restrict__ gamma, const float* __restrict__ beta,
    void* __restrict__ outp, const float* __restrict__ bsel, int esel)
{
  constexpr int C = CPG*8;
  constexpr int V = CPG/8;            // f16x8 vectors per t-row in this group
  int b = blockIdx.x >> 3, g = blockIdx.x & 7;
  float w = 1.f;
  if (bsel){ w = bsel[b*8 + esel]; if (w == 0.f) return; }

  __shared__ f16 tile[T*CPG];
  __shared__ float rs[8];
  __shared__ float mv[2];

  const f16* base = xin + (size_t)b*T*C + g*CPG;
  float sum = 0.f, ss = 0.f;
  for (int i = threadIdx.x; i < T*V; i += 256){
    int t = i / V, v = i - (i/V)*V;
    f16x8 xv = *(const f16x8*)(base + (size_t)t*C + v*8);
    *(f16x8*)(tile + (size_t)i*8) = xv;
    #pragma unroll
    for (int k=0;k<8;++k){ float f = (float)xv[k]; sum += f; ss += f*f; }
  }
  #pragma unroll
  for (int off=32; off; off>>=1){ sum += __shfl_down(sum, off); ss += __shfl_down(ss, off); }
  int wave = threadIdx.x >> 6, lane = threadIdx.x & 63;
  if (lane == 0){ rs[wave] = sum; rs[4+wave] = ss; }
  __syncthreads();
  if (threadIdx.x == 0){
    float S = rs[0]+rs[1]+rs[2]+rs[3], Q = rs[4]+rs[5]+rs[6]+rs[7];
    constexpr float N = (float)(CPG*T);
    float m = S/N;
    float var = Q/N - m*m;
    mv[0] = m; mv[1] = rsqrtf(var + 1e-5f);
  }
  __syncthreads();
  float m = mv[0], rstd = mv[1];

  for (int i = threadIdx.x; i < T*V; i += 256){
    int t = i / V, v = i - (i/V)*V;
    f16x8 xv = *(const f16x8*)(tile + (size_t)i*8);
    int gc0 = g*CPG + v*8;
    float o[8];
    #pragma unroll
    for (int k=0; k<8; ++k){
      float xn = ((float)xv[k]-m)*rstd*gamma[gc0+k] + beta[gc0+k];
      o[k] = geluf(xn);
    }
    if constexpr (MODE == 0){
      f16x8 h8;
      #pragma unroll
      for (int k=0;k<8;++k) h8[k] = (f16)o[k];
      *(f16x8*)((f16*)outp + (size_t)b*T*C + (size_t)t*C + g*CPG + v*8) = h8;
    } else if constexpr (MODE == 1){
      float* hp = (float*)outp + ((size_t)(b*T+t))*256 + g*CPG + v*8;
      *(f32x4*)hp     = f32x4{o[0],o[1],o[2],o[3]};
      *(f32x4*)(hp+4) = f32x4{o[4],o[5],o[6],o[7]};
    } else {
      float* hp = (float*)outp + ((size_t)(b*T+t))*256 + g*CPG + v*8;
      f32x4 a = *(const f32x4*)hp, c = *(const f32x4*)(hp+4);
      *(f32x4*)hp     = f32x4{a[0]+w*o[0], a[1]+w*o[1], a[2]+w*o[2], a[3]+w*o[3]};
      *(f32x4*)(hp+4) = f32x4{c[0]+w*o[4], c[1]+w*o[5], c[2]+w*o[6], c[3]+w*o[7]};
    }
  }
}

__global__ __launch_bounds__(256) void k_h2f16(const float* __restrict__ src,
                                               f16* __restrict__ dst, int n4){
  int idx = blockIdx.x*256 + threadIdx.x;
  if (idx >= n4) return;
  f32x4 v = *(const f32x4*)(src + (size_t)idx*4);
  f16x4v h = {(f16)v[0],(f16)v[1],(f16)v[2],(f16)v[3]};
  *(f16x4v*)(dst + (size_t)idx*4) = h;
}

// ---------------------------------------------------------------------------
// Router
// ---------------------------------------------------------------------------
__global__ __launch_bounds__(512) void k_gap(const f16* __restrict__ ract,
                                             float* __restrict__ rh){
  int b = blockIdx.x;
  int c = threadIdx.x & 127, st = threadIdx.x >> 7;
  const f16* p = ract + (size_t)b*T*128 + c;
  float s = 0.f;
  for (int t = st; t < T; t += 4) s += (float)p[(size_t)t*128];
  __shared__ float acc[512];
  acc[threadIdx.x] = s;
  __syncthreads();
  if (st == 0) rh[b*128 + c] = (acc[c] + acc[128+c] + acc[256+c] + acc[384+c]) * (1.f/(float)T);
}

__global__ __launch_bounds__(128) void k_router(
    const float* __restrict__ rh,
    const float* __restrict__ m1W, const float* __restrict__ m1b,
    const float* __restrict__ lng, const float* __restrict__ lnb,
    const float* __restrict__ m2W, const float* __restrict__ m2b,
    const float* __restrict__ gW,  const float* __restrict__ gb,
    float* __restrict__ wsel)
{
  int b = blockIdx.x, j = threadIdx.x;
  __shared__ float sbuf[128];
  __shared__ float red[4];
  __shared__ float z2[64];
  sbuf[j] = rh[b*128 + j];
  __syncthreads();
  float acc = m1b[j];
  for (int k=0; k<128; ++k) acc += sbuf[k]*m1W[k*128 + j];
  float s1 = acc, s2 = acc*acc;
  #pragma unroll
  for (int off=32; off; off>>=1){ s1 += __shfl_down(s1, off); s2 += __shfl_down(s2, off); }
  int wid = j >> 6, lane = j & 63;
  if (lane == 0){ red[wid] = s1; red[2+wid] = s2; }
  __syncthreads();
  float S = red[0]+red[1], Q = red[2]+red[3];
  float m = S*(1.f/128.f), var = Q*(1.f/128.f) - m*m;
  float xn = (acc - m)*rsqrtf(var + 1e-5f)*lng[j] + lnb[j];
  float ge = geluf(xn);
  __syncthreads();
  sbuf[j] = ge;
  __syncthreads();
  if (j < 64){
    float a = m2b[j];
    for (int k=0; k<128; ++k) a += sbuf[k]*m2W[k*64 + j];
    z2[j] = a;
  }
  __syncthreads();
  if (j == 0){
    float lg[8];
    for (int e=0; e<8; ++e){
      float a = gb[e];
      for (int k=0; k<64; ++k) a += z2[k]*gW[k*8 + e];
      lg[e] = a;
    }
    float mx = lg[0];
    for (int e=1; e<8; ++e) mx = fmaxf(mx, lg[e]);
    float p[8], sum = 0.f;
    for (int e=0; e<8; ++e){ p[e] = __expf(lg[e]-mx); sum += p[e]; }
    float inv = 1.f/sum;
    for (int e=0; e<8; ++e) p[e] *= inv;
    int i1 = 0;
    for (int e=1; e<8; ++e) if (p[e] > p[i1]) i1 = e;
    int i2 = -1;
    for (int e=0; e<8; ++e){ if (e==i1) continue; if (i2 < 0 || p[e] > p[i2]) i2 = e; }
    float s = p[i1] + p[i2] + 1e-9f;
    for (int e=0; e<8; ++e) wsel[b*8+e] = (e==i1 || e==i2) ? p[e]/s : 0.f;
  }
}

// ---------------------------------------------------------------------------
// Persistent LSTM v4 (gate-fused): 64 WGs x 256 threads, 1 wave/SIMD.
// Thread d owns gate cols {d, 256+d, 512+d, 768+d} = i,f,g,o of h-dim d.
// Pairs [0,PV) of each col in VGPRs (4*PV regs); pairs [PV,128) in LDS
// laid out [pair2][1024] uint2 (lanes-consecutive -> conflict-free b64).
// h double-buffered in LDS (uniform b128 broadcast reads); ONE barrier/step.
// ---------------------------------------------------------------------------
constexpr int PV  = 100;     // row-pairs per column in VGPRs
constexpr int PLR = 14;      // uint2 LDS rows ((128-PV)/2)

DEVI float dot2acc(u32 wu, u32 hu, float acc){
#if __has_builtin(__builtin_amdgcn_fdot2)
  return __builtin_amdgcn_fdot2(__builtin_bit_cast(f16x2, wu),
                                __builtin_bit_cast(f16x2, hu), acc, false);
#else
  f16x2 a = __builtin_bit_cast(f16x2, wu), b = __builtin_bit_cast(f16x2, hu);
  return acc + (float)a.x*(float)b.x + (float)a.y*(float)b.y;
#endif
}

__global__ __attribute__((amdgpu_flat_work_group_size(256,256), amdgpu_waves_per_eu(1,1)))
void k_lstm(const u32* __restrict__ whh, const f16* __restrict__ U,
            float* __restrict__ hTout)
{
  int b = blockIdx.x, d = threadIdx.x;

  __shared__ uint2 wl2[PLR*1024];            // 112 KB
  __shared__ __align__(16) u16 hpA[256];
  __shared__ __align__(16) u16 hpB[256];

  u32 wi[PV], wf[PV], wg[PV], wo[PV];
  #pragma unroll
  for (int i=0; i<PV; ++i){
    wi[i] = whh[(size_t)i*1024 + d];
    wf[i] = whh[(size_t)i*1024 + 256 + d];
    wg[i] = whh[(size_t)i*1024 + 512 + d];
    wo[i] = whh[(size_t)i*1024 + 768 + d];
  }
  for (int i = d; i < PLR*1024; i += 256){
    int p2 = i >> 10, c = i & 1023;
    wl2[i] = uint2{ whh[(size_t)(PV+2*p2)*1024 + c],
                    whh[(size_t)(PV+2*p2+1)*1024 + c] };
  }
  hpA[d] = 0;

  float cst = 0.f, hst = 0.f;
  const f16* Ub = U + (size_t)b*T*1024 + d;
  float ui = (float)Ub[0], uf = (float)Ub[256], ug = (float)Ub[512], uo = (float)Ub[768];
  __syncthreads();

  const u16* rd = hpA;
  u16* wr = hpB;

  for (int t=0; t<T; ++t){
    float ai = ui, af = uf, ag = ug, ao = uo;
    if (t+1 < T){
      const f16* un = Ub + (size_t)(t+1)*1024;
      ui = (float)un[0]; uf = (float)un[256]; ug = (float)un[512]; uo = (float)un[768];
    }
    const uint4* hp4 = (const uint4*)rd;
    #pragma unroll
    for (int q=0; q<PV/4; ++q){
      uint4 hq = hp4[q];
      ai = dot2acc(wi[4*q+0], hq.x, ai); af = dot2acc(wf[4*q+0], hq.x, af);
      ag = dot2acc(wg[4*q+0], hq.x, ag); ao = dot2acc(wo[4*q+0], hq.x, ao);
      ai = dot2acc(wi[4*q+1], hq.y, ai); af = dot2acc(wf[4*q+1], hq.y, af);
      ag = dot2acc(wg[4*q+1], hq.y, ag); ao = dot2acc(wo[4*q+1], hq.y, ao);
      ai = dot2acc(wi[4*q+2], hq.z, ai); af = dot2acc(wf[4*q+2], hq.z, af);
      ag = dot2acc(wg[4*q+2], hq.z, ag); ao = dot2acc(wo[4*q+2], hq.z, ao);
      ai = dot2acc(wi[4*q+3], hq.w, ai); af = dot2acc(wf[4*q+3], hq.w, af);
      ag = dot2acc(wg[4*q+3], hq.w, ag); ao = dot2acc(wo[4*q+3], hq.w, ao);
    }
    #pragma unroll
    for (int k=0; k<7; ++k){
      uint4 hq = hp4[PV/4 + k];
      uint2 aI0 = wl2[(2*k)*1024 + d],       aI1 = wl2[(2*k+1)*1024 + d];
      uint2 aF0 = wl2[(2*k)*1024 + 256 + d], aF1 = wl2[(2*k+1)*1024 + 256 + d];
      uint2 aG0 = wl2[(2*k)*1024 + 512 + d], aG1 = wl2[(2*k+1)*1024 + 512 + d];
      uint2 aO0 = wl2[(2*k)*1024 + 768 + d], aO1 = wl2[(2*k+1)*1024 + 768 + d];
      ai = dot2acc(aI0.x, hq.x, ai); ai = dot2acc(aI0.y, hq.y, ai);
      ai = dot2acc(aI1.x, hq.z, ai); ai = dot2acc(aI1.y, hq.w, ai);
      af = dot2acc(aF0.x, hq.x, af); af = dot2acc(aF0.y, hq.y, af);
      af = dot2acc(aF1.x, hq.z, af); af = dot2acc(aF1.y, hq.w, af);
      ag = dot2acc(aG0.x, hq.x, ag); ag = dot2acc(aG0.y, hq.y, ag);
      ag = dot2acc(aG1.x, hq.z, ag); ag = dot2acc(aG1.y, hq.w, ag);
      ao = dot2acc(aO0.x, hq.x, ao); ao = dot2acc(aO0.y, hq.y, ao);
      ao = dot2acc(aO1.x, hq.z, ao); ao = dot2acc(aO1.y, hq.w, ao);
    }
    cst = fsig(af)*cst + fsig(ai)*ftanh(ag);
    hst = fsig(ao)*ftanh(cst);
    wr[d] = __builtin_bit_cast(u16, (f16)hst);
    __syncthreads();
    const u16* nrd = wr; wr = (u16*)rd; rd = nrd;
  }
  hTout[b*256 + d] = hst;
}

__global__ __launch_bounds__(256) void k_head(const float* __restrict__ hT,
    const float* __restrict__ Wc, const float* __restrict__ bc,
    float* __restrict__ out)
{
  int b = blockIdx.x, j = threadIdx.x;
  __shared__ float hs[256];
  hs[j] = hT[b*256 + j];
  __syncthreads();
  if (j < NC){
    float a = bc[j];
    for (int k=0; k<256; ++k) a += hs[k]*Wc[k*NC + j];
    out[b*NC + j] = a;
  }
}

// ---------------------------------------------------------------------------
extern "C" void kernel_launch(void* const* d_in, const int* in_sizes, int n_in,
                              void* d_out, int out_size, void* d_ws, size_t ws_size,
                              hipStream_t stream)
{
  if (ws_size < WS_TOTAL) return;

  const float* x    = (const float*)d_in[0];
  const float* eW1  = (const float*)d_in[1];
  const float* eg1  = (const float*)d_in[2];
  const float* eb1  = (const float*)d_in[3];
  const float* eW2  = (const float*)d_in[4];
  const float* eg2  = (const float*)d_in[5];
  const float* eb2  = (const float*)d_in[6];
  const float* eW3  = (const float*)d_in[7];
  const float* eg3  = (const float*)d_in[8];
  const float* eb3  = (const float*)d_in[9];
  const float* sW1  = (const float*)d_in[10];
  const float* sg1  = (const float*)d_in[11];
  const float* sb1  = (const float*)d_in[12];
  const float* sW2  = (const float*)d_in[13];
  const float* sg2  = (const float*)d_in[14];
  const float* sb2  = (const float*)d_in[15];
  const float* sW3  = (const float*)d_in[16];
  const float* sg3  = (const float*)d_in[17];
  const float* sb3  = (const float*)d_in[18];
  const float* rW   = (const float*)d_in[19];
  const float* rg   = (const float*)d_in[20];
  const float* rb   = (const float*)d_in[21];
  const float* rm1W = (const float*)d_in[22];
  const float* rm1b = (const float*)d_in[23];
  const float* rlng = (const float*)d_in[24];
  const float* rlnb = (const float*)d_in[25];
  const float* rm2W = (const float*)d_in[26];
  const float* rm2b = (const float*)d_in[27];
  const float* gW   = (const float*)d_in[28];
  const float* gb   = (const float*)d_in[29];
  const float* Wih  = (const float*)d_in[30];
  const float* Whh  = (const float*)d_in[31];
  const float* blst = (const float*)d_in[32];
  const float* Wc   = (const float*)d_in[33];
  const float* bc   = (const float*)d_in[34];

  char* ws = (char*)d_ws;
  f16*  ws1   = (f16*)(ws + OFF_WS1);
  f16*  ws2   = (f16*)(ws + OFF_WS2);
  f16*  ws3   = (f16*)(ws + OFF_WS3);
  f16*  we1   = (f16*)(ws + OFF_WE1);
  f16*  we2   = (f16*)(ws + OFF_WE2);
  f16*  we3   = (f16*)(ws + OFF_WE3);
  f16*  wr    = (f16*)(ws + OFF_WR);
  f16*  wih   = (f16*)(ws + OFF_WIH);
  u32*  whh   = (u32*)(ws + OFF_WHH);
  f16*  act0  = (f16*)(ws + OFF_ACT0);
  f16*  a1    = (f16*)(ws + OFF_A1);
  f16*  a2    = (f16*)(ws + OFF_A2);
  f16*  ract  = (f16*)(ws + OFF_RACT);
  f16*  convb = (f16*)(ws + OFF_CONV);
  float* hmix  = (float*)(ws + OFF_HMIX);
  f16*  amix  = (f16*)(ws + OFF_AMIX);
  f16*  Ubuf  = (f16*)(ws + OFF_U);
  float* rh    = (float*)(ws + OFF_RH);
  float* wsel  = (float*)(ws + OFF_WSEL);
  float* hTb   = (float*)(ws + OFF_HT);

  // ---- prep ----
  k_prep_w<<<(2349056 + 255)/256, 256, 0, stream>>>(eW1,eW2,eW3,sW1,sW2,sW3,rW,Wih,Whh,ws);
  k_prep_x<<<(B*T*32 + 255)/256, 256, 0, stream>>>(x, ws);

  // ---- router ----
  k_conv<32,5><<<dim3(512,2), 256, 0, stream>>>(act0, wr, convb, nullptr, nullptr, 0, 128);
  k_gn<16,0><<<B*8, 256, 0, stream>>>(convb, rg, rb, ract, nullptr, 0);
  k_gap<<<B, 512, 0, stream>>>(ract, rh);
  k_router<<<B, 128, 0, stream>>>(rh, rm1W, rm1b, rlng, rlnb, rm2W, rm2b, gW, gb, wsel);

  // ---- shared expert ----
  k_conv<32,5><<<dim3(512,1), 256, 0, stream>>>(act0, ws1, convb, nullptr, nullptr, 0, 64);
  k_gn<8,0><<<B*8, 256, 0, stream>>>(convb, sg1, sb1, a1, nullptr, 0);
  k_conv<64,5><<<dim3(512,2), 256, 0, stream>>>(a1, ws2, convb, nullptr, nullptr, 0, 128);
  k_gn<16,0><<<B*8, 256, 0, stream>>>(convb, sg2, sb2, a2, nullptr, 0);
  k_conv<128,5><<<dim3(512,4), 256, 0, stream>>>(a2, ws3, convb, nullptr, nullptr, 0, 256);
  k_gn<32,1><<<B*8, 256, 0, stream>>>(convb, sg3, sb3, hmix, nullptr, 0);

  // ---- experts (top-2 skip) ----
  for (int e=0; e<8; ++e){
    k_conv<32,5><<<dim3(512,1), 256, 0, stream>>>(act0, we1 + (size_t)e*10240, convb, nullptr, wsel, e, 64);
    k_gn<8,0><<<B*8, 256, 0, stream>>>(convb, eg1 + e*64, eb1 + e*64, a1, wsel, e);
    k_conv<64,5><<<dim3(512,2), 256, 0, stream>>>(a1, we2 + (size_t)e*40960, convb, nullptr, wsel, e, 128);
    k_gn<16,0><<<B*8, 256, 0, stream>>>(convb, eg2 + e*128, eb2 + e*128, a2, wsel, e);
    k_conv<128,5><<<dim3(512,4), 256, 0, stream>>>(a2, we3 + (size_t)e*163840, convb, nullptr, wsel, e, 256);
    k_gn<32,2><<<B*8, 256, 0, stream>>>(convb, eg3 + e*256, eb3 + e*256, hmix, wsel, e);
  }

  // ---- LSTM ----
  k_h2f16<<<(B*T*256/4 + 255)/256, 256, 0, stream>>>(hmix, amix, B*T*256/4);
  k_conv<256,1><<<dim3(512,16), 256, 0, stream>>>(amix, wih, Ubuf, blst, nullptr, 0, 1024);
  k_lstm<<<B, 256, 0, stream>>>(whh, Ubuf, hTb);
  k_head<<<B, 256, 0, stream>>>(hTb, Wc, bc, (float*)d_out);
}

// Round 5
// 1905.011 us; speedup vs baseline: 1.5644x; 1.5644x over previous
//
#include <hip/hip_runtime.h>
#include <cstdint>
#include <cstddef>

// ---------------------------------------------------------------------------
// DeepCNNLSTM_EncoderMOE on MI355X (gfx950)
// Round 5: LSTM v5 — 512 thr (2 waves/SIMD), thread owns 2 gate cols.
// 100 pairs/col in VGPR (200 regs, fits arch cap 256 w/ waves_per_eu(2,2)),
// 28 pairs in LDS [pair][1024] (stride-1 b32 = conflict-free), gbuf exchange.
// Scratch-spill signature (35 GB FETCH) must vanish.
// ---------------------------------------------------------------------------

#define DEVI __device__ __forceinline__

typedef _Float16 f16;
typedef _Float16 f16x8 __attribute__((ext_vector_type(8)));
typedef _Float16 f16x2 __attribute__((ext_vector_type(2)));
typedef _Float16 f16x4v __attribute__((ext_vector_type(4)));
typedef float    f32x4 __attribute__((ext_vector_type(4)));
typedef unsigned int u32;
typedef unsigned short u16;

static constexpr int B   = 64;
static constexpr int T   = 512;
static constexpr int NC  = 10;

// ---- workspace layout (bytes) ----
constexpr size_t SZ_WS1 = (size_t)5*64*32*2;
constexpr size_t SZ_WS2 = (size_t)5*128*64*2;
constexpr size_t SZ_WS3 = (size_t)5*256*128*2;
constexpr size_t SZ_WE1 = 8*SZ_WS1;
constexpr size_t SZ_WE2 = 8*SZ_WS2;
constexpr size_t SZ_WE3 = 8*SZ_WS3;
constexpr size_t SZ_WR  = (size_t)5*128*32*2;
constexpr size_t SZ_WIH = (size_t)1024*256*2;
constexpr size_t SZ_WHH = (size_t)128*1024*4;
constexpr size_t SZ_ACT0 = (size_t)B*T*32*2;
constexpr size_t SZ_A1   = (size_t)B*T*64*2;
constexpr size_t SZ_A2   = (size_t)B*T*128*2;
constexpr size_t SZ_RACT = (size_t)B*T*128*2;
constexpr size_t SZ_CONV = (size_t)B*T*256*2;
constexpr size_t SZ_HMIX = (size_t)B*T*256*4;
constexpr size_t SZ_AMIX = (size_t)B*T*256*2;
constexpr size_t SZ_U    = (size_t)B*T*1024*2;
constexpr size_t SZ_STAT = (size_t)B*8*2*4;
constexpr size_t SZ_RH   = (size_t)B*128*4;
constexpr size_t SZ_WSEL = (size_t)B*8*4;
constexpr size_t SZ_HT   = (size_t)B*256*4;

constexpr size_t OFF_WS1  = 0;
constexpr size_t OFF_WS2  = OFF_WS1 + SZ_WS1;
constexpr size_t OFF_WS3  = OFF_WS2 + SZ_WS2;
constexpr size_t OFF_WE1  = OFF_WS3 + SZ_WS3;
constexpr size_t OFF_WE2  = OFF_WE1 + SZ_WE1;
constexpr size_t OFF_WE3  = OFF_WE2 + SZ_WE2;
constexpr size_t OFF_WR   = OFF_WE3 + SZ_WE3;
constexpr size_t OFF_WIH  = OFF_WR  + SZ_WR;
constexpr size_t OFF_WHH  = OFF_WIH + SZ_WIH;
constexpr size_t OFF_ACT0 = OFF_WHH + SZ_WHH;
constexpr size_t OFF_A1   = OFF_ACT0 + SZ_ACT0;
constexpr size_t OFF_A2   = OFF_A1 + SZ_A1;
constexpr size_t OFF_RACT = OFF_A2 + SZ_A2;
constexpr size_t OFF_CONV = OFF_RACT + SZ_RACT;
constexpr size_t OFF_HMIX = OFF_CONV + SZ_CONV;
constexpr size_t OFF_AMIX = OFF_HMIX + SZ_HMIX;
constexpr size_t OFF_U    = OFF_AMIX + SZ_AMIX;
constexpr size_t OFF_STAT = OFF_U + SZ_U;
constexpr size_t OFF_RH   = OFF_STAT + SZ_STAT;
constexpr size_t OFF_WSEL = OFF_RH + SZ_RH;
constexpr size_t OFF_HT   = OFF_WSEL + SZ_WSEL;
constexpr size_t WS_TOTAL = OFF_HT + SZ_HT;

DEVI float geluf(float x){ return 0.5f*x*(1.f + erff(x*0.70710678118654752f)); }
DEVI float fsig(float x){ return 1.f/(1.f + __expf(-x)); }
DEVI float ftanh(float x){ float e = __expf(-2.f*x); return (1.f-e)/(1.f+e); }

// ---------------------------------------------------------------------------
// Weight prep
// ---------------------------------------------------------------------------
DEVI void fill_convw(f16* dst, const float* src, int COUT, int CI, int CIP, int idx){
  int s  = idx / (COUT*CIP);
  int r  = idx - s*(COUT*CIP);
  int co = r / CIP;
  int ci = r - co*CIP;
  float v = (ci < CI) ? src[((size_t)co*CI + ci)*5 + s] : 0.f;
  dst[idx] = (f16)v;
}

__global__ __launch_bounds__(256) void k_prep_w(
    const float* eW1, const float* eW2, const float* eW3,
    const float* sW1, const float* sW2, const float* sW3, const float* rW,
    const float* Wih, const float* Whh, char* ws)
{
  int i = blockIdx.x*256 + threadIdx.x;
  if (i < 10240){ fill_convw((f16*)(ws+OFF_WS1), sW1, 64, 16, 32, i); return; } i -= 10240;
  if (i < 40960){ fill_convw((f16*)(ws+OFF_WS2), sW2, 128, 64, 64, i); return; } i -= 40960;
  if (i < 163840){ fill_convw((f16*)(ws+OFF_WS3), sW3, 256, 128, 128, i); return; } i -= 163840;
  if (i < 81920){ int e=i/10240, r=i-e*10240;
    fill_convw((f16*)(ws+OFF_WE1)+ (size_t)e*10240, eW1 + (size_t)e*64*16*5, 64, 16, 32, r); return; } i -= 81920;
  if (i < 327680){ int e=i/40960, r=i-e*40960;
    fill_convw((f16*)(ws+OFF_WE2)+ (size_t)e*40960, eW2 + (size_t)e*128*64*5, 128, 64, 64, r); return; } i -= 327680;
  if (i < 1310720){ int e=i/163840, r=i-e*163840;
    fill_convw((f16*)(ws+OFF_WE3)+ (size_t)e*163840, eW3 + (size_t)e*163840, 256, 128, 128, r); return; } i -= 1310720;
  if (i < 20480){ fill_convw((f16*)(ws+OFF_WR), rW, 128, 16, 32, i); return; } i -= 20480;
  if (i < 262144){ // W_ih (256,1024) -> [j][k]
    int j = i >> 8, k = i & 255;
    ((f16*)(ws+OFF_WIH))[i] = (f16)Wih[(size_t)k*1024 + j]; return; } i -= 262144;
  if (i < 131072){ // W_hh (256,1024) -> packed row-pairs [pair][1024]
    int i2 = i >> 10, j = i & 1023;
    f16 a = (f16)Whh[(size_t)(2*i2)*1024 + j];
    f16 b = (f16)Whh[(size_t)(2*i2+1)*1024 + j];
    u32 u = (u32)__builtin_bit_cast(unsigned short, a)
          | ((u32)__builtin_bit_cast(unsigned short, b) << 16);
    ((u32*)(ws+OFF_WHH))[i] = u; return; }
}

__global__ __launch_bounds__(256) void k_prep_x(const float* __restrict__ x, char* ws){
  int idx = blockIdx.x*256 + threadIdx.x;
  if (idx >= B*T*32) return;
  int b = idx/(T*32); int r = idx - b*(T*32); int t = r >> 5; int c = r & 31;
  f16 v = (c < 16) ? (f16)x[((size_t)b*16 + c)*T + t] : (f16)0.f;
  ((f16*)(ws+OFF_ACT0))[idx] = v;
}

// ---------------------------------------------------------------------------
// Conv / GEMM via MFMA f16
// ---------------------------------------------------------------------------
template<int CIN, int NSHIFT>
__global__ __launch_bounds__(256) void k_conv(
    const f16* __restrict__ act, const f16* __restrict__ wt,
    f16* __restrict__ outp, const float* __restrict__ bias,
    const float* __restrict__ bsel, int esel, int COUT)
{
  int mt = blockIdx.x;
  int b  = mt >> 3;
  int t0 = (mt & 7) << 6;
  if (bsel && bsel[b*8 + esel] == 0.f) return;
  int n0   = blockIdx.y << 6;
  int tid  = threadIdx.x;
  int wave = tid >> 6, lane = tid & 63;
  int lr = lane & 15, lk = lane >> 4;

  f32x4 acc[4];
  #pragma unroll
  for (int nf=0; nf<4; ++nf) acc[nf] = f32x4{0.f,0.f,0.f,0.f};

  const f16* abase = act + (size_t)b*T*CIN;
  int trow = t0 + wave*16 + lr;

  #pragma unroll
  for (int s=0; s<NSHIFT; ++s){
    int tg = (NSHIFT==5) ? (trow + s - 2) : trow;
    bool valid = (unsigned)tg < (unsigned)T;
    const f16* arow = abase + (long)tg*CIN + lk*8;
    #pragma unroll
    for (int c0=0; c0<CIN; c0+=32){
      f16x8 af = {(f16)0,(f16)0,(f16)0,(f16)0,(f16)0,(f16)0,(f16)0,(f16)0};
      if (valid) af = *(const f16x8*)(arow + c0);
      #pragma unroll
      for (int nf=0; nf<4; ++nf){
        int col = n0 + nf*16 + lr;
        f16x8 bf = *(const f16x8*)(wt + ((size_t)s*COUT + col)*CIN + c0 + lk*8);
        acc[nf] = __builtin_amdgcn_mfma_f32_16x16x32_f16(af, bf, acc[nf], 0, 0, 0);
      }
    }
  }

  #pragma unroll
  for (int nf=0; nf<4; ++nf){
    int col = n0 + nf*16 + lr;
    float bv = bias ? bias[col] : 0.f;
    #pragma unroll
    for (int r=0; r<4; ++r){
      int trw = t0 + wave*16 + lk*4 + r;
      size_t o = ((size_t)b*T + trw)*COUT + col;
      outp[o] = (f16)(acc[nf][r] + bv);
    }
  }
}

// ---------------------------------------------------------------------------
// Fused GroupNorm (stats + normalize + GELU) per (b,g) via LDS tile.
// MODE 0: write f16 act. MODE 1: hmix = v (f32). MODE 2: hmix += w*v.
// ---------------------------------------------------------------------------
template<int CPG, int MODE>
__global__ __launch_bounds__(256) void k_gn(
    const f16* __restrict__ xin,
    const float* __restrict__ gamma, const float* __restrict__ beta,
    void* __restrict__ outp, const float* __restrict__ bsel, int esel)
{
  constexpr int C = CPG*8;
  constexpr int V = CPG/8;
  int b = blockIdx.x >> 3, g = blockIdx.x & 7;
  float w = 1.f;
  if (bsel){ w = bsel[b*8 + esel]; if (w == 0.f) return; }

  __shared__ f16 tile[T*CPG];
  __shared__ float rs[8];
  __shared__ float mv[2];

  const f16* base = xin + (size_t)b*T*C + g*CPG;
  float sum = 0.f, ss = 0.f;
  for (int i = threadIdx.x; i < T*V; i += 256){
    int t = i / V, v = i - (i/V)*V;
    f16x8 xv = *(const f16x8*)(base + (size_t)t*C + v*8);
    *(f16x8*)(tile + (size_t)i*8) = xv;
    #pragma unroll
    for (int k=0;k<8;++k){ float f = (float)xv[k]; sum += f; ss += f*f; }
  }
  #pragma unroll
  for (int off=32; off; off>>=1){ sum += __shfl_down(sum, off); ss += __shfl_down(ss, off); }
  int wave = threadIdx.x >> 6, lane = threadIdx.x & 63;
  if (lane == 0){ rs[wave] = sum; rs[4+wave] = ss; }
  __syncthreads();
  if (threadIdx.x == 0){
    float S = rs[0]+rs[1]+rs[2]+rs[3], Q = rs[4]+rs[5]+rs[6]+rs[7];
    constexpr float N = (float)(CPG*T);
    float m = S/N;
    float var = Q/N - m*m;
    mv[0] = m; mv[1] = rsqrtf(var + 1e-5f);
  }
  __syncthreads();
  float m = mv[0], rstd = mv[1];

  for (int i = threadIdx.x; i < T*V; i += 256){
    int t = i / V, v = i - (i/V)*V;
    f16x8 xv = *(const f16x8*)(tile + (size_t)i*8);
    int gc0 = g*CPG + v*8;
    float o[8];
    #pragma unroll
    for (int k=0; k<8; ++k){
      float xn = ((float)xv[k]-m)*rstd*gamma[gc0+k] + beta[gc0+k];
      o[k] = geluf(xn);
    }
    if constexpr (MODE == 0){
      f16x8 h8;
      #pragma unroll
      for (int k=0;k<8;++k) h8[k] = (f16)o[k];
      *(f16x8*)((f16*)outp + (size_t)b*T*C + (size_t)t*C + g*CPG + v*8) = h8;
    } else if constexpr (MODE == 1){
      float* hp = (float*)outp + ((size_t)(b*T+t))*256 + g*CPG + v*8;
      *(f32x4*)hp     = f32x4{o[0],o[1],o[2],o[3]};
      *(f32x4*)(hp+4) = f32x4{o[4],o[5],o[6],o[7]};
    } else {
      float* hp = (float*)outp + ((size_t)(b*T+t))*256 + g*CPG + v*8;
      f32x4 a = *(const f32x4*)hp, c = *(const f32x4*)(hp+4);
      *(f32x4*)hp     = f32x4{a[0]+w*o[0], a[1]+w*o[1], a[2]+w*o[2], a[3]+w*o[3]};
      *(f32x4*)(hp+4) = f32x4{c[0]+w*o[4], c[1]+w*o[5], c[2]+w*o[6], c[3]+w*o[7]};
    }
  }
}

__global__ __launch_bounds__(256) void k_h2f16(const float* __restrict__ src,
                                               f16* __restrict__ dst, int n4){
  int idx = blockIdx.x*256 + threadIdx.x;
  if (idx >= n4) return;
  f32x4 v = *(const f32x4*)(src + (size_t)idx*4);
  f16x4v h = {(f16)v[0],(f16)v[1],(f16)v[2],(f16)v[3]};
  *(f16x4v*)(dst + (size_t)idx*4) = h;
}

// ---------------------------------------------------------------------------
// Router
// ---------------------------------------------------------------------------
__global__ __launch_bounds__(512) void k_gap(const f16* __restrict__ ract,
                                             float* __restrict__ rh){
  int b = blockIdx.x;
  int c = threadIdx.x & 127, st = threadIdx.x >> 7;
  const f16* p = ract + (size_t)b*T*128 + c;
  float s = 0.f;
  for (int t = st; t < T; t += 4) s += (float)p[(size_t)t*128];
  __shared__ float acc[512];
  acc[threadIdx.x] = s;
  __syncthreads();
  if (st == 0) rh[b*128 + c] = (acc[c] + acc[128+c] + acc[256+c] + acc[384+c]) * (1.f/(float)T);
}

__global__ __launch_bounds__(128) void k_router(
    const float* __restrict__ rh,
    const float* __restrict__ m1W, const float* __restrict__ m1b,
    const float* __restrict__ lng, const float* __restrict__ lnb,
    const float* __restrict__ m2W, const float* __restrict__ m2b,
    const float* __restrict__ gW,  const float* __restrict__ gb,
    float* __restrict__ wsel)
{
  int b = blockIdx.x, j = threadIdx.x;
  __shared__ float sbuf[128];
  __shared__ float red[4];
  __shared__ float z2[64];
  sbuf[j] = rh[b*128 + j];
  __syncthreads();
  float acc = m1b[j];
  for (int k=0; k<128; ++k) acc += sbuf[k]*m1W[k*128 + j];
  float s1 = acc, s2 = acc*acc;
  #pragma unroll
  for (int off=32; off; off>>=1){ s1 += __shfl_down(s1, off); s2 += __shfl_down(s2, off); }
  int wid = j >> 6, lane = j & 63;
  if (lane == 0){ red[wid] = s1; red[2+wid] = s2; }
  __syncthreads();
  float S = red[0]+red[1], Q = red[2]+red[3];
  float m = S*(1.f/128.f), var = Q*(1.f/128.f) - m*m;
  float xn = (acc - m)*rsqrtf(var + 1e-5f)*lng[j] + lnb[j];
  float ge = geluf(xn);
  __syncthreads();
  sbuf[j] = ge;
  __syncthreads();
  if (j < 64){
    float a = m2b[j];
    for (int k=0; k<128; ++k) a += sbuf[k]*m2W[k*64 + j];
    z2[j] = a;
  }
  __syncthreads();
  if (j == 0){
    float lg[8];
    for (int e=0; e<8; ++e){
      float a = gb[e];
      for (int k=0; k<64; ++k) a += z2[k]*gW[k*8 + e];
      lg[e] = a;
    }
    float mx = lg[0];
    for (int e=1; e<8; ++e) mx = fmaxf(mx, lg[e]);
    float p[8], sum = 0.f;
    for (int e=0; e<8; ++e){ p[e] = __expf(lg[e]-mx); sum += p[e]; }
    float inv = 1.f/sum;
    for (int e=0; e<8; ++e) p[e] *= inv;
    int i1 = 0;
    for (int e=1; e<8; ++e) if (p[e] > p[i1]) i1 = e;
    int i2 = -1;
    for (int e=0; e<8; ++e){ if (e==i1) continue; if (i2 < 0 || p[e] > p[i2]) i2 = e; }
    float s = p[i1] + p[i2] + 1e-9f;
    for (int e=0; e<8; ++e) wsel[b*8+e] = (e==i1 || e==i2) ? p[e]/s : 0.f;
  }
}

// ---------------------------------------------------------------------------
// Persistent LSTM v5: 64 WGs x 512 threads (8 waves, 2/SIMD).
// Thread (half = j>>8, d = j&255) owns cols {half*256+d, 512+half*256+d}:
// half0 -> (i,g) of dim d, half1 -> (f,o) of dim d.
// Pairs [0,100) per col in VGPRs (200 regs, <=256 arch cap via waves_per_eu(2,2));
// pairs [100,128) in LDS [pair][1024] u32 (stride-1 b32 reads, conflict-free).
// h double-buffered (128 packed u32); f,o exchanged via 2KB gbuf; 2 barriers/step.
// ---------------------------------------------------------------------------
constexpr int PV5 = 100;     // pairs per column in VGPRs
constexpr int PLQ = 7;       // LDS pair-quads (28 pairs)

DEVI float dot2acc(u32 wu, u32 hu, float acc){
#if __has_builtin(__builtin_amdgcn_fdot2)
  return __builtin_amdgcn_fdot2(__builtin_bit_cast(f16x2, wu),
                                __builtin_bit_cast(f16x2, hu), acc, false);
#else
  f16x2 a = __builtin_bit_cast(f16x2, wu), b = __builtin_bit_cast(f16x2, hu);
  return acc + (float)a.x*(float)b.x + (float)a.y*(float)b.y;
#endif
}

__global__ __attribute__((amdgpu_flat_work_group_size(512,512), amdgpu_waves_per_eu(2,2)))
void k_lstm(const u32* __restrict__ whh, const f16* __restrict__ U,
            float* __restrict__ hTout)
{
  int b = blockIdx.x, j = threadIdx.x;
  int d = j & 255, half = j >> 8;
  int colA = half*256 + d;        // i (half0) or f (half1)
  int colB = 512 + colA;          // g (half0) or o (half1)

  __shared__ u32 wl[PLQ*4*1024];              // 112 KB: pairs [100,128)
  __shared__ __align__(16) u32 hbuf[2][128];  // packed f16 h, double-buffered
  __shared__ float gbF[256], gbO[256];

  u32 wA[PV5], wB[PV5];
  #pragma unroll
  for (int i=0; i<PV5; ++i){
    wA[i] = whh[(size_t)i*1024 + colA];
    wB[i] = whh[(size_t)i*1024 + colB];
  }
  for (int idx = j; idx < PLQ*4*1024; idx += 512){
    int p = idx >> 10, c = idx & 1023;
    wl[idx] = whh[(size_t)(PV5+p)*1024 + c];
  }
  if (j < 128) hbuf[0][j] = 0u;

  float cst = 0.f, hst = 0.f;
  const f16* Ub = U + (size_t)b*T*1024;
  float uA = (float)Ub[colA], uB = (float)Ub[colB];
  __syncthreads();

  int cur = 0;
  for (int t=0; t<T; ++t){
    float aA = uA, aB = uB;
    if (t+1 < T){
      const f16* un = Ub + (size_t)(t+1)*1024;
      uA = (float)un[colA]; uB = (float)un[colB];
    }
    const uint4* hp4 = (const uint4*)hbuf[cur];
    #pragma unroll
    for (int q=0; q<PV5/4; ++q){
      uint4 hq = hp4[q];
      aA = dot2acc(wA[4*q+0], hq.x, aA); aB = dot2acc(wB[4*q+0], hq.x, aB);
      aA = dot2acc(wA[4*q+1], hq.y, aA); aB = dot2acc(wB[4*q+1], hq.y, aB);
      aA = dot2acc(wA[4*q+2], hq.z, aA); aB = dot2acc(wB[4*q+2], hq.z, aB);
      aA = dot2acc(wA[4*q+3], hq.w, aA); aB = dot2acc(wB[4*q+3], hq.w, aB);
    }
    #pragma unroll
    for (int k=0; k<PLQ; ++k){
      uint4 hq = hp4[PV5/4 + k];
      u32 a0 = wl[(4*k+0)*1024 + colA], b0 = wl[(4*k+0)*1024 + colB];
      u32 a1 = wl[(4*k+1)*1024 + colA], b1 = wl[(4*k+1)*1024 + colB];
      u32 a2 = wl[(4*k+2)*1024 + colA], b2 = wl[(4*k+2)*1024 + colB];
      u32 a3 = wl[(4*k+3)*1024 + colA], b3 = wl[(4*k+3)*1024 + colB];
      aA = dot2acc(a0, hq.x, aA); aB = dot2acc(b0, hq.x, aB);
      aA = dot2acc(a1, hq.y, aA); aB = dot2acc(b1, hq.y, aB);
      aA = dot2acc(a2, hq.z, aA); aB = dot2acc(b2, hq.z, aB);
      aA = dot2acc(a3, hq.w, aA); aB = dot2acc(b3, hq.w, aB);
    }
    if (half){ gbF[d] = aA; gbO[d] = aB; }
    __syncthreads();
    if (!half){
      float gi = aA, gg = aB, gf = gbF[d], go = gbO[d];
      cst = fsig(gf)*cst + fsig(gi)*ftanh(gg);
      hst = fsig(go)*ftanh(cst);
      u16* hn = (u16*)hbuf[cur^1];
      hn[d] = __builtin_bit_cast(u16, (f16)hst);
    }
    __syncthreads();
    cur ^= 1;
  }
  if (!half) hTout[b*256 + d] = hst;
}

__global__ __launch_bounds__(256) void k_head(const float* __restrict__ hT,
    const float* __restrict__ Wc, const float* __restrict__ bc,
    float* __restrict__ out)
{
  int b = blockIdx.x, j = threadIdx.x;
  __shared__ float hs[256];
  hs[j] = hT[b*256 + j];
  __syncthreads();
  if (j < NC){
    float a = bc[j];
    for (int k=0; k<256; ++k) a += hs[k]*Wc[k*NC + j];
    out[b*NC + j] = a;
  }
}

// ---------------------------------------------------------------------------
extern "C" void kernel_launch(void* const* d_in, const int* in_sizes, int n_in,
                              void* d_out, int out_size, void* d_ws, size_t ws_size,
                              hipStream_t stream)
{
  if (ws_size < WS_TOTAL) return;

  const float* x    = (const float*)d_in[0];
  const float* eW1  = (const float*)d_in[1];
  const float* eg1  = (const float*)d_in[2];
  const float* eb1  = (const float*)d_in[3];
  const float* eW2  = (const float*)d_in[4];
  const float* eg2  = (const float*)d_in[5];
  const float* eb2  = (const float*)d_in[6];
  const float* eW3  = (const float*)d_in[7];
  const float* eg3  = (const float*)d_in[8];
  const float* eb3  = (const float*)d_in[9];
  const float* sW1  = (const float*)d_in[10];
  const float* sg1  = (const float*)d_in[11];
  const float* sb1  = (const float*)d_in[12];
  const float* sW2  = (const float*)d_in[13];
  const float* sg2  = (const float*)d_in[14];
  const float* sb2  = (const float*)d_in[15];
  const float* sW3  = (const float*)d_in[16];
  const float* sg3  = (const float*)d_in[17];
  const float* sb3  = (const float*)d_in[18];
  const float* rW   = (const float*)d_in[19];
  const float* rg   = (const float*)d_in[20];
  const float* rb   = (const float*)d_in[21];
  const float* rm1W = (const float*)d_in[22];
  const float* rm1b = (const float*)d_in[23];
  const float* rlng = (const float*)d_in[24];
  const float* rlnb = (const float*)d_in[25];
  const float* rm2W = (const float*)d_in[26];
  const float* rm2b = (const float*)d_in[27];
  const float* gW   = (const float*)d_in[28];
  const float* gb   = (const float*)d_in[29];
  const float* Wih  = (const float*)d_in[30];
  const float* Whh  = (const float*)d_in[31];
  const float* blst = (const float*)d_in[32];
  const float* Wc   = (const float*)d_in[33];
  const float* bc   = (const float*)d_in[34];

  char* ws = (char*)d_ws;
  f16*  ws1   = (f16*)(ws + OFF_WS1);
  f16*  ws2   = (f16*)(ws + OFF_WS2);
  f16*  ws3   = (f16*)(ws + OFF_WS3);
  f16*  we1   = (f16*)(ws + OFF_WE1);
  f16*  we2   = (f16*)(ws + OFF_WE2);
  f16*  we3   = (f16*)(ws + OFF_WE3);
  f16*  wr    = (f16*)(ws + OFF_WR);
  f16*  wih   = (f16*)(ws + OFF_WIH);
  u32*  whh   = (u32*)(ws + OFF_WHH);
  f16*  act0  = (f16*)(ws + OFF_ACT0);
  f16*  a1    = (f16*)(ws + OFF_A1);
  f16*  a2    = (f16*)(ws + OFF_A2);
  f16*  ract  = (f16*)(ws + OFF_RACT);
  f16*  convb = (f16*)(ws + OFF_CONV);
  float* hmix  = (float*)(ws + OFF_HMIX);
  f16*  amix  = (f16*)(ws + OFF_AMIX);
  f16*  Ubuf  = (f16*)(ws + OFF_U);
  float* rh    = (float*)(ws + OFF_RH);
  float* wsel  = (float*)(ws + OFF_WSEL);
  float* hTb   = (float*)(ws + OFF_HT);

  // ---- prep ----
  k_prep_w<<<(2349056 + 255)/256, 256, 0, stream>>>(eW1,eW2,eW3,sW1,sW2,sW3,rW,Wih,Whh,ws);
  k_prep_x<<<(B*T*32 + 255)/256, 256, 0, stream>>>(x, ws);

  // ---- router ----
  k_conv<32,5><<<dim3(512,2), 256, 0, stream>>>(act0, wr, convb, nullptr, nullptr, 0, 128);
  k_gn<16,0><<<B*8, 256, 0, stream>>>(convb, rg, rb, ract, nullptr, 0);
  k_gap<<<B, 512, 0, stream>>>(ract, rh);
  k_router<<<B, 128, 0, stream>>>(rh, rm1W, rm1b, rlng, rlnb, rm2W, rm2b, gW, gb, wsel);

  // ---- shared expert ----
  k_conv<32,5><<<dim3(512,1), 256, 0, stream>>>(act0, ws1, convb, nullptr, nullptr, 0, 64);
  k_gn<8,0><<<B*8, 256, 0, stream>>>(convb, sg1, sb1, a1, nullptr, 0);
  k_conv<64,5><<<dim3(512,2), 256, 0, stream>>>(a1, ws2, convb, nullptr, nullptr, 0, 128);
  k_gn<16,0><<<B*8, 256, 0, stream>>>(convb, sg2, sb2, a2, nullptr, 0);
  k_conv<128,5><<<dim3(512,4), 256, 0, stream>>>(a2, ws3, convb, nullptr, nullptr, 0, 256);
  k_gn<32,1><<<B*8, 256, 0, stream>>>(convb, sg3, sb3, hmix, nullptr, 0);

  // ---- experts (top-2 skip) ----
  for (int e=0; e<8; ++e){
    k_conv<32,5><<<dim3(512,1), 256, 0, stream>>>(act0, we1 + (size_t)e*10240, convb, nullptr, wsel, e, 64);
    k_gn<8,0><<<B*8, 256, 0, stream>>>(convb, eg1 + e*64, eb1 + e*64, a1, wsel, e);
    k_conv<64,5><<<dim3(512,2), 256, 0, stream>>>(a1, we2 + (size_t)e*40960, convb, nullptr, wsel, e, 128);
    k_gn<16,0><<<B*8, 256, 0, stream>>>(convb, eg2 + e*128, eb2 + e*128, a2, wsel, e);
    k_conv<128,5><<<dim3(512,4), 256, 0, stream>>>(a2, we3 + (size_t)e*163840, convb, nullptr, wsel, e, 256);
    k_gn<32,2><<<B*8, 256, 0, stream>>>(convb, eg3 + e*256, eb3 + e*256, hmix, wsel, e);
  }

  // ---- LSTM ----
  k_h2f16<<<(B*T*256/4 + 255)/256, 256, 0, stream>>>(hmix, amix, B*T*256/4);
  k_conv<256,1><<<dim3(512,16), 256, 0, stream>>>(amix, wih, Ubuf, blst, nullptr, 0, 1024);
  k_lstm<<<B, 512, 0, stream>>>(whh, Ubuf, hTb);
  k_head<<<B, 256, 0, stream>>>(hTb, Wc, bc, (float*)d_out);
}